// Round 2
// baseline (1093.031 us; speedup 1.0000x reference)
//
#include <hip/hip_runtime.h>
#include <hip/hip_bf16.h>

// Problem constants
constexpr int NB  = 2;     // batch
constexpr int TT  = 2048;  // T
constexpr int MEM = 2048;  // M (xl memory length)
constexpr int CC  = 1024;  // C
constexpr int NH  = 16;    // heads
constexpr int HD  = 64;    // head dim
constexpr int TKK = 4096;  // T + M
constexpr int BT  = NB * TT;

typedef __attribute__((ext_vector_type(8))) short short8;
typedef __attribute__((ext_vector_type(4))) float floatx4;

struct __align__(8) us4 { unsigned short x, y, z, w; };

__device__ __forceinline__ unsigned short f2bf(float f) {
  union { float f; unsigned int u; } v; v.f = f;
  return (unsigned short)((v.u + 0x7fffu + ((v.u >> 16) & 1u)) >> 16);
}
__device__ __forceinline__ unsigned short f2bf_fast(float f) {  // round-half-up (for P)
  union { float f; unsigned int u; } v; v.f = f;
  return (unsigned short)((v.u + 0x8000u) >> 16);
}

// ---------------------------------------------------------------------------
// prep_w: Wq/Wk/Wv fp32 (k,n) -> Wt bf16 transposed (n,k), via LDS 64x64 tiles.
// ---------------------------------------------------------------------------
__global__ __launch_bounds__(256) void prep_w_k(
    const float* __restrict__ Wq, const float* __restrict__ Wk,
    const float* __restrict__ Wv, unsigned short* __restrict__ Wt) {
  __shared__ unsigned short T[64][72];
  const int n0 = blockIdx.x * 64, k0 = blockIdx.y * 64, z = blockIdx.z;
  const float* __restrict__ W = (z == 0) ? Wq : ((z == 1) ? Wk : Wv);
  const int tid = threadIdx.x;
#pragma unroll
  for (int s = 0; s < 4; s++) {
    int kr = (tid >> 4) + s * 16, nc = (tid & 15) << 2;
    float4 w4 = *(const float4*)&W[(size_t)(k0 + kr) * CC + n0 + nc];
    T[nc + 0][kr] = f2bf(w4.x);
    T[nc + 1][kr] = f2bf(w4.y);
    T[nc + 2][kr] = f2bf(w4.z);
    T[nc + 3][kr] = f2bf(w4.w);
  }
  __syncthreads();
#pragma unroll
  for (int i = 0; i < 2; i++) {
    int e = tid + i * 256;
    int n = e >> 3, kc = (e & 7) << 3;
    *(short8*)&Wt[(size_t)z * CC * CC + (size_t)(n0 + n) * CC + k0 + kc] =
        *(const short8*)&T[n][kc];
  }
}

// ---------------------------------------------------------------------------
// prep_xl: xl (B,M,2,C) fp32 -> k_ws natural bf16 (B,H,TK,D) rows 0..M-1 and
// v_ws tile-blocked transposed+swizzled: (B,H,kblk, d*64 + ((kg^(d&7))*8|k&7))
// ---------------------------------------------------------------------------
__global__ __launch_bounds__(256) void prep_xl_k(const float* __restrict__ xl,
    unsigned short* __restrict__ k_ws, unsigned short* __restrict__ v_ws) {
  __shared__ unsigned short T[64][72];
  const int mt = blockIdx.x, h = blockIdx.y, b = blockIdx.z;
  const int tid = threadIdx.x;
  const int bh = b * NH + h;
#pragma unroll
  for (int s = 0; s < 4; s++) {
    int m = (tid >> 4) + s * 16, d4 = (tid & 15) << 2;
    size_t src = ((size_t)(b * MEM + mt * 64 + m)) * 2 * CC + h * 64 + d4;
    float4 kk = *(const float4*)&xl[src];
    float4 vv = *(const float4*)&xl[src + CC];
    *(us4*)&k_ws[((size_t)bh * TKK + mt * 64 + m) * HD + d4] =
        us4{f2bf(kk.x), f2bf(kk.y), f2bf(kk.z), f2bf(kk.w)};
    T[d4 + 0][m] = f2bf(vv.x);
    T[d4 + 1][m] = f2bf(vv.y);
    T[d4 + 2][m] = f2bf(vv.z);
    T[d4 + 3][m] = f2bf(vv.w);
  }
  __syncthreads();
  const size_t vbase = ((size_t)bh * 64 + mt) * 4096;
#pragma unroll
  for (int i = 0; i < 2; i++) {
    int e = tid + i * 256;
    int d = e >> 3, mc = (e & 7) << 3;
    int grp = (mc >> 3) ^ (d & 7);
    *(short8*)&v_ws[vbase + d * 64 + (grp << 3)] = *(const short8*)&T[d][mc];
  }
}

// ---------------------------------------------------------------------------
// gemm_qkv: A = x (4096x1024 fp32 -> bf16 in staging), B = Wt (bf16, (n,k)).
// 128x128 tile, BK=32. Epilogue scatters q/k (natural) + v (blocked swizzled),
// k/v also to new_xl (fp32 out).
// ---------------------------------------------------------------------------
__global__ __launch_bounds__(256) void gemm_qkv_k(
    const float* __restrict__ x, const unsigned short* __restrict__ Wt,
    unsigned short* __restrict__ q_ws, unsigned short* __restrict__ k_ws,
    unsigned short* __restrict__ v_ws, float* __restrict__ out_xl) {
  __shared__ unsigned short As[128][40];
  __shared__ unsigned short Bs[128][40];
  const int tid = threadIdx.x;
  const int m0 = blockIdx.x * 128;
  const int nb = blockIdx.y;  // 0..23
  const int sel = nb >> 3;    // 0=q 1=k 2=v
  const int n0 = (nb & 7) * 128;
  const unsigned short* __restrict__ Wsel = Wt + (size_t)sel * CC * CC;
  const int wave = tid >> 6, lane = tid & 63;
  const int mh = (wave >> 1) * 64, nh = (wave & 1) * 64;
  const int ln = lane & 15, qd = lane >> 4;
  const floatx4 fzero = {0.f, 0.f, 0.f, 0.f};

  floatx4 acc[4][4];
#pragma unroll
  for (int i = 0; i < 4; i++)
#pragma unroll
    for (int j = 0; j < 4; j++) acc[i][j] = fzero;

  for (int kt = 0; kt < CC; kt += 32) {
    __syncthreads();
#pragma unroll
    for (int i = 0; i < 4; i++) {
      int e = tid + i * 256;
      int row = e >> 3, kc = (e & 7) << 2;
      float4 a4 = *(const float4*)&x[(size_t)(m0 + row) * CC + kt + kc];
      *(us4*)&As[row][kc] = us4{f2bf(a4.x), f2bf(a4.y), f2bf(a4.z), f2bf(a4.w)};
    }
#pragma unroll
    for (int i = 0; i < 2; i++) {
      int e = tid + i * 256;
      int n = e >> 2, kc = (e & 3) << 3;
      *(short8*)&Bs[n][kc] = *(const short8*)&Wsel[(size_t)(n0 + n) * CC + kt + kc];
    }
    __syncthreads();
    short8 af[4], bfr[4];
#pragma unroll
    for (int mf = 0; mf < 4; mf++) af[mf]  = *(const short8*)&As[mh + mf * 16 + ln][qd * 8];
#pragma unroll
    for (int nf = 0; nf < 4; nf++) bfr[nf] = *(const short8*)&Bs[nh + nf * 16 + ln][qd * 8];
#pragma unroll
    for (int mf = 0; mf < 4; mf++)
#pragma unroll
      for (int nf = 0; nf < 4; nf++)
        acc[mf][nf] = __builtin_amdgcn_mfma_f32_16x16x32_bf16(af[mf], bfr[nf], acc[mf][nf], 0, 0, 0);
  }

#pragma unroll
  for (int mf = 0; mf < 4; mf++) {
#pragma unroll
    for (int nf = 0; nf < 4; nf++) {
      int gn = n0 + nh + nf * 16 + ln;
      int h = gn >> 6, d = gn & 63;
#pragma unroll
      for (int r = 0; r < 4; r++) {
        int gm = m0 + mh + mf * 16 + qd * 4 + r;
        int b = gm >> 11, t = gm & 2047;
        int bh = b * NH + h;
        float val = acc[mf][nf][r];
        unsigned short bv = f2bf(val);
        if (sel == 0) {
          q_ws[((size_t)bh * TT + t) * HD + d] = bv;
        } else if (sel == 1) {
          k_ws[((size_t)bh * TKK + MEM + t) * HD + d] = bv;
          out_xl[(((size_t)(b * TT + t)) * 2 + 0) * CC + gn] = val;
        } else {
          int kk = MEM + t;
          int kblk = kk >> 6;
          int grp = ((t >> 3) & 7) ^ (d & 7);
          v_ws[((size_t)bh * 64 + kblk) * 4096 + d * 64 + (grp << 3) + (t & 7)] = bv;
          out_xl[(((size_t)(b * TT + t)) * 2 + 1) * CC + gn] = val;
        }
      }
    }
  }
}

// ---------------------------------------------------------------------------
// attn: flash attention, one (q-tile 64, head, batch) per block. Twin-batch
// blocks are adjacent in blockIdx.x so the shared bias read hits L2/L3.
// Register-prefetch of next K/V tile overlaps compute. Sum via ones-MFMA.
// ---------------------------------------------------------------------------
__global__ __launch_bounds__(256, 4) void attn_k(
    const unsigned short* __restrict__ q_ws, const unsigned short* __restrict__ k_ws,
    const unsigned short* __restrict__ v_ws, const float* __restrict__ rel,
    unsigned short* __restrict__ wv_ws) {
  __shared__ unsigned short Ks[64][72];       // natural [kcol][dim], pad 8
  __shared__ unsigned short Vs[64 * 64];      // pre-transposed+swizzled (flat copy)
  __shared__ unsigned short Ps[4][16][64];    // per-wave P scratch, swizzled
  const int bx = blockIdx.x;                  // qt*2 + b
  const int b = bx & 1, qt = bx >> 1;
  const int h = blockIdx.y;
  const int tid = threadIdx.x;
  const int wave = tid >> 6, lane = tid & 63;
  const int ln = lane & 15, qd = lane >> 4;
  const int q0 = qt * 64;
  const int qrow_w = q0 + wave * 16;
  const int bh = b * NH + h;
  const floatx4 fzero = {0.f, 0.f, 0.f, 0.f};

  const unsigned short* __restrict__ kbaseP = k_ws + (size_t)bh * TKK * HD;
  const unsigned short* __restrict__ vbaseP = v_ws + (size_t)bh * 64 * 4096;
  const float* __restrict__ relBase = rel + ((size_t)h * TT + qrow_w + qd * 4) * TKK + ln;

  short8 qf[2];
#pragma unroll
  for (int ks = 0; ks < 2; ks++)
    qf[ks] = *(const short8*)&q_ws[((size_t)bh * TT + qrow_w + ln) * HD + ks * 32 + qd * 8];

  short8 ones;
#pragma unroll
  for (int j = 0; j < 8; j++) ones[j] = (short)0x3F80;  // bf16 1.0

  floatx4 of[4], osum = fzero;
  float mrow[4];
#pragma unroll
  for (int nf = 0; nf < 4; nf++) of[nf] = fzero;
#pragma unroll
  for (int r = 0; r < 4; r++) mrow[r] = -1e30f;

  const int ntiles = qt + 33;
  short8 kpre0, kpre1, vpre0, vpre1;
  {
    const unsigned short* kp = kbaseP;
    const unsigned short* vp = vbaseP;
    kpre0 = *(const short8*)(kp + tid * 8);
    kpre1 = *(const short8*)(kp + tid * 8 + 2048);
    vpre0 = *(const short8*)(vp + tid * 8);
    vpre1 = *(const short8*)(vp + tid * 8 + 2048);
  }

  for (int kt = 0; kt < ntiles; kt++) {
    const int kbase = kt * 64;
    __syncthreads();
    {
      int r0 = tid >> 3, c0 = (tid & 7) << 3;
      *(short8*)&Ks[r0][c0] = kpre0;
      *(short8*)&Ks[r0 + 32][c0] = kpre1;
      *(short8*)&Vs[tid * 8] = vpre0;
      *(short8*)&Vs[tid * 8 + 2048] = vpre1;
    }
    __syncthreads();
    if (kt + 1 < ntiles) {
      const unsigned short* kp = kbaseP + (kt + 1) * 4096;
      const unsigned short* vp = vbaseP + (kt + 1) * 4096;
      kpre0 = *(const short8*)(kp + tid * 8);
      kpre1 = *(const short8*)(kp + tid * 8 + 2048);
      vpre0 = *(const short8*)(vp + tid * 8);
      vpre1 = *(const short8*)(vp + tid * 8 + 2048);
    }

    float bias[4][4];
#pragma unroll
    for (int nf = 0; nf < 4; nf++)
#pragma unroll
      for (int r = 0; r < 4; r++)
        bias[nf][r] = relBase[(size_t)r * TKK + kbase + nf * 16];

    floatx4 sacc[4];
#pragma unroll
    for (int nf = 0; nf < 4; nf++) sacc[nf] = fzero;
#pragma unroll
    for (int ks = 0; ks < 2; ks++)
#pragma unroll
      for (int nf = 0; nf < 4; nf++) {
        short8 kf = *(const short8*)&Ks[nf * 16 + ln][ks * 32 + qd * 8];
        sacc[nf] = __builtin_amdgcn_mfma_f32_16x16x32_bf16(qf[ks], kf, sacc[nf], 0, 0, 0);
      }

    float sv[4][4];
#pragma unroll
    for (int nf = 0; nf < 4; nf++)
#pragma unroll
      for (int r = 0; r < 4; r++)
        sv[nf][r] = (sacc[nf][r] + bias[nf][r]) * 0.125f;

    if (kt == ntiles - 1) {
#pragma unroll
      for (int nf = 0; nf < 4; nf++)
#pragma unroll
        for (int r = 0; r < 4; r++) {
          int kcol = kbase + nf * 16 + ln;
          int qrow = qrow_w + qd * 4 + r;
          if (kcol > qrow + MEM) sv[nf][r] = -1e30f;
        }
    }

#pragma unroll
    for (int r = 0; r < 4; r++) {
      float mx = fmaxf(fmaxf(sv[0][r], sv[1][r]), fmaxf(sv[2][r], sv[3][r]));
#pragma unroll
      for (int off = 8; off >= 1; off >>= 1)
        mx = fmaxf(mx, __shfl_xor(mx, off, 64));
      float mnew = fmaxf(mrow[r], mx);
      float alpha = __expf(mrow[r] - mnew);
      mrow[r] = mnew;
#pragma unroll
      for (int nf = 0; nf < 4; nf++) {
        float p = __expf(sv[nf][r] - mnew);
        sv[nf][r] = p;
        of[nf][r] *= alpha;
      }
      osum[r] *= alpha;
    }

    // P (C-layout) -> per-wave LDS, swizzled
#pragma unroll
    for (int nf = 0; nf < 4; nf++)
#pragma unroll
      for (int r = 0; r < 4; r++) {
        int row = qd * 4 + r;
        int col = nf * 16 + ln;
        int slot = ((col >> 3) ^ (row & 7) ^ (row >> 3)) & 7;
        Ps[wave][row][(slot << 3) | (col & 7)] = f2bf_fast(sv[nf][r]);
      }

#pragma unroll
    for (int ks = 0; ks < 2; ks++) {
      int g = ks * 4 + qd;
      int pslot = (g ^ (ln & 7) ^ (ln >> 3)) & 7;
      short8 pf = *(const short8*)&Ps[wave][ln][pslot << 3];
      osum = __builtin_amdgcn_mfma_f32_16x16x32_bf16(pf, ones, osum, 0, 0, 0);
#pragma unroll
      for (int nf = 0; nf < 4; nf++) {
        int dd = nf * 16 + ln;
        int vgrp = g ^ (dd & 7);
        short8 vf = *(const short8*)&Vs[dd * 64 + (vgrp << 3)];
        of[nf] = __builtin_amdgcn_mfma_f32_16x16x32_bf16(pf, vf, of[nf], 0, 0, 0);
      }
    }
  }

  float inv[4];
#pragma unroll
  for (int r = 0; r < 4; r++) inv[r] = 1.f / osum[r];
#pragma unroll
  for (int nf = 0; nf < 4; nf++)
#pragma unroll
    for (int r = 0; r < 4; r++)
      wv_ws[((size_t)(b * TT) + qrow_w + qd * 4 + r) * CC + h * 64 + nf * 16 + ln] =
          f2bf(of[nf][r] * inv[r]);
}

// ---------------------------------------------------------------------------
// gemm_out: out = wv @ Wp + bp (A bf16 ws, B fp32->bf16 staging, out fp32)
// ---------------------------------------------------------------------------
__global__ __launch_bounds__(256) void gemm_out_k(
    const unsigned short* __restrict__ a_bf, const float* __restrict__ Wp,
    const float* __restrict__ bp, float* __restrict__ out) {
  __shared__ unsigned short As[128][40];
  __shared__ unsigned short Bs[128][40];
  const int tid = threadIdx.x;
  const int m0 = blockIdx.x * 128;
  const int n0 = blockIdx.y * 128;
  const int wave = tid >> 6, lane = tid & 63;
  const int mh = (wave >> 1) * 64, nh = (wave & 1) * 64;
  const int ln = lane & 15, qd = lane >> 4;
  const floatx4 fzero = {0.f, 0.f, 0.f, 0.f};

  floatx4 acc[4][4];
#pragma unroll
  for (int i = 0; i < 4; i++)
#pragma unroll
    for (int j = 0; j < 4; j++) acc[i][j] = fzero;

  for (int kt = 0; kt < CC; kt += 32) {
    __syncthreads();
#pragma unroll
    for (int i = 0; i < 2; i++) {
      int e = tid + i * 256;
      int row = e >> 2, c0 = (e & 3) << 3;
      *(short8*)&As[row][c0] = *(const short8*)&a_bf[(size_t)(m0 + row) * CC + kt + c0];
    }
#pragma unroll
    for (int i = 0; i < 4; i++) {
      int e = tid + i * 256;
      int n = e & 127, kg = e >> 7;
      const float* p = &Wp[(size_t)(kt + kg * 4) * CC + n0 + n];
      float b0 = p[0], b1 = p[CC], b2 = p[2 * CC], b3 = p[3 * CC];
      *(us4*)&Bs[n][kg * 4] = us4{f2bf(b0), f2bf(b1), f2bf(b2), f2bf(b3)};
    }
    __syncthreads();
    short8 af[4], bfr[4];
#pragma unroll
    for (int mf = 0; mf < 4; mf++) af[mf]  = *(const short8*)&As[mh + mf * 16 + ln][qd * 8];
#pragma unroll
    for (int nf = 0; nf < 4; nf++) bfr[nf] = *(const short8*)&Bs[nh + nf * 16 + ln][qd * 8];
#pragma unroll
    for (int mf = 0; mf < 4; mf++)
#pragma unroll
      for (int nf = 0; nf < 4; nf++)
        acc[mf][nf] = __builtin_amdgcn_mfma_f32_16x16x32_bf16(af[mf], bfr[nf], acc[mf][nf], 0, 0, 0);
  }

#pragma unroll
  for (int mf = 0; mf < 4; mf++)
#pragma unroll
    for (int nf = 0; nf < 4; nf++) {
      int gn = n0 + nh + nf * 16 + ln;
      float bias = bp[gn];
#pragma unroll
      for (int r = 0; r < 4; r++) {
        int gm = m0 + mh + mf * 16 + qd * 4 + r;
        out[(size_t)gm * CC + gn] = acc[mf][nf][r] + bias;
      }
    }
}

// ---------------------------------------------------------------------------
// Workspace map (48 MB total):
//   [ 0,  8M)  q_ws  bf16 (B,H,T,D)
//   [ 8, 24M)  k_ws  bf16 (B,H,TK,D) natural
//   [24, 40M)  v_ws  bf16 tile-blocked transposed+swizzled (B,H,64,4096)
//   [40, 46M)  Wt    bf16 (3, n, k)  -- dead after gemm_qkv
//   [40, 48M)  wv_ws bf16 (B*T, C)   -- written by attn (after Wt is dead)
// ---------------------------------------------------------------------------
extern "C" void kernel_launch(void* const* d_in, const int* in_sizes, int n_in,
                              void* d_out, int out_size, void* d_ws, size_t ws_size,
                              hipStream_t stream) {
  const float* rel = (const float*)d_in[0];
  const float* x   = (const float*)d_in[1];
  const float* xl  = (const float*)d_in[2];
  const float* Wq  = (const float*)d_in[3];
  const float* Wk  = (const float*)d_in[4];
  const float* Wv  = (const float*)d_in[5];
  const float* Wp  = (const float*)d_in[6];
  const float* bp  = (const float*)d_in[7];
  float* out    = (float*)d_out;
  float* out_xl = out + (size_t)BT * CC;

  char* ws = (char*)d_ws;
  unsigned short* q_ws  = (unsigned short*)(ws);
  unsigned short* k_ws  = (unsigned short*)(ws + (size_t)8  * 1024 * 1024);
  unsigned short* v_ws  = (unsigned short*)(ws + (size_t)24 * 1024 * 1024);
  unsigned short* Wt    = (unsigned short*)(ws + (size_t)40 * 1024 * 1024);
  unsigned short* wv_ws = (unsigned short*)(ws + (size_t)40 * 1024 * 1024);

  prep_w_k<<<dim3(16, 16, 3), dim3(256), 0, stream>>>(Wq, Wk, Wv, Wt);
  prep_xl_k<<<dim3(32, 16, 2), dim3(256), 0, stream>>>(xl, k_ws, v_ws);
  gemm_qkv_k<<<dim3(32, 24), dim3(256), 0, stream>>>(x, Wt, q_ws, k_ws, v_ws, out_xl);
  attn_k<<<dim3(64, 16), dim3(256), 0, stream>>>(q_ws, k_ws, v_ws, rel, wv_ws);
  gemm_out_k<<<dim3(32, 8), dim3(256), 0, stream>>>(wv_ws, Wp, bp, out);
}